// Round 4
// baseline (49023.001 us; speedup 1.0000x reference)
//
#include <hip/hip_runtime.h>
#include <cstdint>

#define TT 256
#define BB 128
#define HH 256
#define LL 3
#define LN_EPS 1e-5f

// ---------------- helpers ----------------

__device__ __forceinline__ float fast_sigmoid(float x) {
    return 1.f / (1.f + __expf(-x));
}
__device__ __forceinline__ float fast_tanh(float x) {
    float xc = fminf(fmaxf(x, -15.f), 15.f);
    float e = __expf(2.f * xc);
    return 1.f - 2.f / (e + 1.f);
}
__device__ __forceinline__ float relu(float x) { return fmaxf(x, 0.f); }

// dual reduction over 1024 threads (16 waves). One barrier; every thread
// sums the 16 wave-partials itself (LDS broadcast reads). Caller must
// ping-pong the scr buffer between consecutive calls.
__device__ __forceinline__ float2 red2(float a, float b, float* scr, int tid) {
#pragma unroll
    for (int o = 32; o > 0; o >>= 1) {
        a += __shfl_down(a, o);
        b += __shfl_down(b, o);
    }
    if ((tid & 63) == 0) { int w = tid >> 6; scr[w] = a; scr[16 + w] = b; }
    __syncthreads();
    float s = 0.f, s2 = 0.f;
#pragma unroll
    for (int i = 0; i < 16; i++) { s += scr[i]; s2 += scr[16 + i]; }
    return make_float2(s, s2);
}

// Device-wide timestep alignment barrier (PERFORMANCE ONLY — no data crosses
// WGs; correctness does not depend on it). Monotonic counter in d_ws, zeroed
// by hipMemsetAsync before each kernel launch. All 128 WGs (1024 thr each)
// are co-resident on 256 CUs, so spinning cannot deadlock.
__device__ __forceinline__ void step_barrier(int* cnt, int target, int tid) {
    __syncthreads();
    if (tid == 0) {
        __hip_atomic_fetch_add(cnt, 1, __ATOMIC_RELAXED, __HIP_MEMORY_SCOPE_AGENT);
        while (__hip_atomic_load(cnt, __ATOMIC_RELAXED, __HIP_MEMORY_SCOPE_AGENT) < target) {
            __builtin_amdgcn_s_sleep(8);
        }
    }
    __syncthreads();
}

// y_raw[n] = sum_k xs[k]*W[k][n]; W fp32 row-major [K,N] read as float4
// (4 columns per thread). G-way K-split; partials to dst[g*N + n].
// nQ*G should equal 1024 (all threads busy). No bias (consumer adds).
template <int K, int N, int G>
__device__ __forceinline__ void matvec4(const float* __restrict__ Wp,
                                        const float* __restrict__ xs,
                                        float* __restrict__ dst, int t) {
    constexpr int nQ = N / 4;          // float4 column groups
    constexpr int kc = K / G;
    if (t < nQ * G) {
        int g = t / nQ;                // nQ is pow2 -> shift
        int j = t - g * nQ;
        const float4* W = (const float4*)Wp + (size_t)(g * kc) * nQ + j;
        const float* xp = xs + g * kc;
        float4 acc = make_float4(0.f, 0.f, 0.f, 0.f);
#pragma unroll 8
        for (int k = 0; k < kc; k++) {
            float4 w = W[(size_t)k * nQ];
            float xk = xp[k];
            acc.x = fmaf(w.x, xk, acc.x);
            acc.y = fmaf(w.y, xk, acc.y);
            acc.z = fmaf(w.z, xk, acc.z);
            acc.w = fmaf(w.w, xk, acc.w);
        }
        *((float4*)(dst + g * N) + j) = acc;
    }
}

// ---------------- main kernel ----------------

struct Args {
    const float *params, *disp;
    const float *embed_b, *embed_g, *embed_beta;
    const float *skip_b;
    const float *gates_b;
    const float *inln_g, *inln_b, *hln_g, *hln_b, *sln_g, *sln_b;
    const float *ab1, *aw2, *ab2;
    const float *rb1, *rb2, *rln_g, *rln_b;
    const float *ob1, *oln_g, *oln_b, *ow2, *ob2;
    const float *gw, *a1w, *r1w, *r2w, *ew, *sw, *o1w;
    float* out;
    int* bar;
};

__global__ __launch_bounds__(1024) void xlstm_kernel(Args A) {
    const int tid = threadIdx.x;
    const int b = blockIdx.x;

    __shared__ __align__(16) float g4[4096];    // matvec partial scratch (16KB)
    __shared__ __align__(16) float xnhn[512];   // [xn,hn] / relu(r1) / head input
    __shared__ __align__(16) float cv[HH];      // staged c for a1 matvec
    __shared__ __align__(16) float hv[HH];      // staged h for r1 matvec
    __shared__ float sk[128];                   // skip activation
    __shared__ float xt[17];                    // timestep input features
    __shared__ float scrA[32], scrB[32];        // ping-pong reduction scratch

    // per-neuron registers (threads 0..255 own neuron `tid`)
    float xr = 0.f;
    float hreg[LL] = {0.f, 0.f, 0.f};
    float creg[LL] = {0.f, 0.f, 0.f};

    int rp = 0;   // reduction ping-pong counter (const-folds under unroll)
    auto RED = [&](float a, float bb) {
        float2 r = red2(a, bb, (rp & 1) ? scrB : scrA, tid);
        rp++;
        return r;
    };

    if (tid < 16) xt[1 + tid] = A.params[b * 16 + tid];
    __syncthreads();

    for (int t = 0; t < TT; t++) {
        if (tid == 0) xt[0] = A.disp[b * TT + t];
        __syncthreads();   // xt ready; g4/xnhn free from prev step

        // ---- embed (tid<256) & skip (256..383), each thread owns a column ----
        float ev = 0.f;
        if (tid < 256) {
            float a = 0.f;
#pragma unroll
            for (int k = 0; k < 17; k++) a = fmaf(A.ew[k * 256 + tid], xt[k], a);
            ev = a + A.embed_b[tid];
        } else if (tid < 384) {
            int j = tid - 256;
            float a = 0.f;
#pragma unroll
            for (int k = 0; k < 17; k++) a = fmaf(A.sw[k * 128 + j], xt[k], a);
            sk[j] = relu(a + A.skip_b[j]);
        }
        float2 f2 = RED(ev, ev * ev);   // tid>=256 contribute ev=0
        float mu = f2.x / HH;
        float inv = rsqrtf(f2.y / HH - mu * mu + LN_EPS);
        if (tid < 256) xr = relu((ev - mu) * inv * A.embed_g[tid] + A.embed_beta[tid]);

#pragma unroll
        for (int l = 0; l < LL; l++) {
            // ---- xn = LN(x), hn = LN(h); stage xnhn + cv ----
            float v = (tid < 256) ? xr : 0.f;
            f2 = RED(v, v * v);
            mu = f2.x / HH; inv = rsqrtf(f2.y / HH - mu * mu + LN_EPS);
            if (tid < 256)
                xnhn[tid] = (v - mu) * inv * A.inln_g[l * HH + tid] + A.inln_b[l * HH + tid];
            float hvv = (tid < 256) ? hreg[l] : 0.f;
            f2 = RED(hvv, hvv * hvv);
            mu = f2.x / HH; inv = rsqrtf(f2.y / HH - mu * mu + LN_EPS);
            if (tid < 256) {
                xnhn[HH + tid] = (hvv - mu) * inv * A.hln_g[l * HH + tid] + A.hln_b[l * HH + tid];
                cv[tid] = creg[l];
            }
            __syncthreads();

            // ---- imp = sigmoid(tanh(c @ aw1 + ab1) @ aw2 + ab2) ----
            matvec4<256, 256, 16>(A.a1w + (size_t)l * (256 * 256), cv, g4, tid);
            __syncthreads();
            v = 0.f;
            if (tid < 256) {
                float s = A.ab1[l * HH + tid];
#pragma unroll
                for (int g = 0; g < 16; g++) s += g4[g * 256 + tid];
                v = fast_tanh(s) * A.aw2[l * HH + tid];
            }
            f2 = RED(v, 0.f);
            float impv = fast_sigmoid(f2.x + A.ab2[l]);
            // RED's barrier separates imp's g4 reads from gates' g4 writes

            // ---- gates = [xn,hn] @ gates_w ----
            matvec4<512, 1024, 4>(A.gw + (size_t)l * (512 * 1024), xnhn, g4, tid);
            __syncthreads();
            v = 0.f;
            float og = 0.f;
            if (tid < 256) {
                const float* gb = A.gates_b + l * 1024;
                float si = gb[tid], sf = gb[256 + tid], sg = gb[512 + tid], so = gb[768 + tid];
#pragma unroll
                for (int g = 0; g < 4; g++) {
                    si += g4[g * 1024 + tid];
                    sf += g4[g * 1024 + 256 + tid];
                    sg += g4[g * 1024 + 512 + tid];
                    so += g4[g * 1024 + 768 + tid];
                }
                float ig = fast_sigmoid(si);
                float fg = fast_sigmoid(sf);
                float gg = fast_tanh(sg);
                og = fast_sigmoid(so);
                v = (fg * creg[l] + ig * gg) * impv;   // c_raw
            }
            f2 = RED(v, v * v);
            mu = f2.x / HH; inv = rsqrtf(f2.y / HH - mu * mu + LN_EPS);
            if (tid < 256) {
                float cn = (v - mu) * inv * A.sln_g[l * HH + tid] + A.sln_b[l * HH + tid];
                creg[l] = cn;
                float hn = og * fast_tanh(cn);
                hreg[l] = hn;
                hv[tid] = hn;
            }
            __syncthreads();   // hv staged (also: gates-epi g4 reads done before r1 writes)

            // ---- residual MLP ----
            matvec4<256, 512, 8>(A.r1w + (size_t)l * (256 * 512), hv, g4, tid);
            __syncthreads();
            if (tid < 512) {
                float s = A.rb1[l * 512 + tid];
#pragma unroll
                for (int g = 0; g < 8; g++) s += g4[g * 512 + tid];
                xnhn[tid] = relu(s);
            }
            __syncthreads();   // xnhn staged; g4 reads done before r2 writes

            matvec4<512, 256, 16>(A.r2w + (size_t)l * (512 * 256), xnhn, g4, tid);
            __syncthreads();
            v = 0.f;
            if (tid < 256) {
                float s = A.rb2[l * HH + tid] + hreg[l];
#pragma unroll
                for (int g = 0; g < 16; g++) s += g4[g * 256 + tid];
                v = s;
            }
            f2 = RED(v, v * v);
            mu = f2.x / HH; inv = rsqrtf(f2.y / HH - mu * mu + LN_EPS);
            if (tid < 256)
                xr = (v - mu) * inv * A.rln_g[l * HH + tid] + A.rln_b[l * HH + tid] + xr;
            // RED's barrier separates r2-epi g4 reads from next use
        }

        // ---- output head ----
        if (tid < 256) xnhn[tid] = xr;
        else if (tid < 384) xnhn[tid] = sk[tid - 256];
        __syncthreads();
        matvec4<384, 128, 32>(A.o1w, xnhn, g4, tid);   // kc=12
        __syncthreads();
        float v = 0.f;
        if (tid < 128) {
            float s = A.ob1[tid];
#pragma unroll
            for (int g = 0; g < 32; g++) s += g4[g * 128 + tid];
            v = s;
        }
        float2 f2o = RED(v, v * v);
        float muo = f2o.x / 128.f;
        float invo = rsqrtf(f2o.y / 128.f - muo * muo + LN_EPS);
        float contrib = 0.f;
        if (tid < 128)
            contrib = relu((v - muo) * invo * A.oln_g[tid] + A.oln_b[tid]) * A.ow2[tid];
        f2o = RED(contrib, 0.f);
        if (tid == 0) A.out[b * TT + t] = f2o.x + A.ob2[0];

        // keep all 128 WGs in the same timestep so the 16 WGs per XCD share
        // one L2-resident copy of each stage's weights (perf only, no data dep)
        step_barrier(A.bar, BB * (t + 1), tid);
    }
}

// ---------------- launch ----------------

extern "C" void kernel_launch(void* const* d_in, const int* in_sizes, int n_in,
                              void* d_out, int out_size, void* d_ws, size_t ws_size,
                              hipStream_t stream) {
    // zero the barrier counter (d_ws is poisoned 0xAA before every launch)
    hipMemsetAsync(d_ws, 0, 64, stream);

    Args A;
    A.params     = (const float*)d_in[0];
    A.disp       = (const float*)d_in[1];
    A.ew         = (const float*)d_in[2];
    A.embed_b    = (const float*)d_in[3];
    A.embed_g    = (const float*)d_in[4];
    A.embed_beta = (const float*)d_in[5];
    A.sw         = (const float*)d_in[6];
    A.skip_b     = (const float*)d_in[7];
    A.gw         = (const float*)d_in[8];
    A.gates_b    = (const float*)d_in[9];
    A.inln_g     = (const float*)d_in[10];
    A.inln_b     = (const float*)d_in[11];
    A.hln_g      = (const float*)d_in[12];
    A.hln_b      = (const float*)d_in[13];
    A.sln_g      = (const float*)d_in[14];
    A.sln_b      = (const float*)d_in[15];
    A.a1w        = (const float*)d_in[16];
    A.ab1        = (const float*)d_in[17];
    A.aw2        = (const float*)d_in[18];
    A.ab2        = (const float*)d_in[19];
    A.r1w        = (const float*)d_in[20];
    A.rb1        = (const float*)d_in[21];
    A.r2w        = (const float*)d_in[22];
    A.rb2        = (const float*)d_in[23];
    A.rln_g      = (const float*)d_in[24];
    A.rln_b      = (const float*)d_in[25];
    A.o1w        = (const float*)d_in[26];
    A.ob1        = (const float*)d_in[27];
    A.oln_g      = (const float*)d_in[28];
    A.oln_b      = (const float*)d_in[29];
    A.ow2        = (const float*)d_in[30];
    A.ob2        = (const float*)d_in[31];
    A.out        = (float*)d_out;
    A.bar        = (int*)d_ws;

    xlstm_kernel<<<BB, 1024, 0, stream>>>(A);
}